// Round 10
// baseline (39.375 us; speedup 1.0000x reference)
//
#include <hip/hip_runtime.h>

namespace {
constexpr int Bn = 64;
constexpr int Ln = 512;
constexpr int Hn = 768;
constexpr int Dn = 16;
}

// ---------------------------------------------------------------------------
// One wave = one task. 1088 blocks x 64 threads; zero barriers, zero LDS.
//   task tid < Bn          : query pooling for batch tid (16x bcast writes)
//   task tid in [Bn, 1088) : doc (b,d) pooling
// Phase 1: stream the task's rows once (3 float4/lane covers all 768 cols),
//          score each row via 6-step shfl_xor; scores kept in a fully-
//          unrolled 32-reg array.
// Softmax: per-lane serial over the register array (all lanes redundantly,
//          no communication). Bias dropped: softmax is shift-invariant under
//          the uniform +bias, and masked entries still underflow to exact 0.
// Phase 2: re-read rows (L2/L3-hot — wave just touched them), FMA into
//          float4 acc, fully unrolled.
// Masked rows are never touched (reference zeroes them and alpha=0 exactly).
// Doc len==0 -> zero-store (reference: uniform softmax x zeroed rows = 0).
// ---------------------------------------------------------------------------
__global__ __launch_bounds__(64) void k_wave(
    const float* __restrict__ hs,
    const float* __restrict__ Wd,
    const float* __restrict__ Wq,
    const int* __restrict__ qlen, const int* __restrict__ slens,
    float* __restrict__ out_doc, float* __restrict__ out_q)
{
    const int lane = threadIdx.x;              // 0..63
    const int tid  = blockIdx.x;               // 0..1087
    const bool isq = (tid < Bn);

    int b, d = 0;
    const float* W;
    if (isq) { b = tid; W = Wq; }
    else     { const int id = tid - Bn; b = id >> 4; d = id & 15; W = Wd; }

    // issue all setup loads together
    const int sv = slens[b * Dn + (lane & 15)];          // lanes hold slens[b,:]
    const int ql = qlen[b];
    const float4 wv0 = *reinterpret_cast<const float4*>(W + lane * 4);
    const float4 wv1 = *reinterpret_cast<const float4*>(W + (lane + 64) * 4);
    const float4 wv2 = *reinterpret_cast<const float4*>(W + (lane + 128) * 4);

    int len, base;
    if (isq) {
        len = ql;                                        // 8..32
        base = 1;
    } else {
        len = __shfl(sv, d, 64);                         // this doc's len
        if (len == 0) {                                  // ~36% of doc tasks
            float4* o = reinterpret_cast<float4*>(out_doc + ((size_t)b * Dn + d) * Hn);
            const float4 z = make_float4(0.f, 0.f, 0.f, 0.f);
            o[lane] = z; o[lane + 64] = z; o[lane + 128] = z;
            return;
        }
        int pref = 0;
#pragma unroll
        for (int k = 0; k < Dn; ++k)
            pref += (k < d) ? __shfl(sv, k, 64) : 0;
        base = ql + 2 + pref;                            // max valid idx 481 < 512
    }
    const float* bp = hs + ((size_t)b * Ln + base) * Hn;

    // ---- phase 1: stream rows, score into register array ----
    float p[32];
#pragma unroll
    for (int s = 0; s < 32; ++s) {
        if (s < len) {                                   // wave-uniform
            const float* r = bp + s * Hn;
            const float4 c0 = *reinterpret_cast<const float4*>(r + lane * 4);
            const float4 c1 = *reinterpret_cast<const float4*>(r + (lane + 64) * 4);
            const float4 c2 = *reinterpret_cast<const float4*>(r + (lane + 128) * 4);
            float v = c0.x * wv0.x + c0.y * wv0.y + c0.z * wv0.z + c0.w * wv0.w
                    + c1.x * wv1.x + c1.y * wv1.y + c1.z * wv1.z + c1.w * wv1.w
                    + c2.x * wv2.x + c2.y * wv2.y + c2.z * wv2.z + c2.w * wv2.w;
#pragma unroll
            for (int off = 32; off; off >>= 1) v += __shfl_xor(v, off);
            p[s] = v;                                    // full-row score, all lanes
        } else {
            p[s] = 0.f;
        }
    }

    // ---- softmax over p[0..len), per-lane serial (no communication) ----
    float m = -INFINITY;
#pragma unroll
    for (int s = 0; s < 32; ++s)
        if (s < len) m = fmaxf(m, p[s]);
    float den = 0.f;
#pragma unroll
    for (int s = 0; s < 32; ++s)
        if (s < len) { p[s] = __expf(p[s] - m); den += p[s]; }
    const float inv = 1.f / den;

    // ---- phase 2: re-read rows (L2/L3-hot), weighted pool ----
    float4 a0 = make_float4(0.f, 0.f, 0.f, 0.f);
    float4 a1 = make_float4(0.f, 0.f, 0.f, 0.f);
    float4 a2 = make_float4(0.f, 0.f, 0.f, 0.f);
#pragma unroll
    for (int s = 0; s < 32; ++s) {
        if (s < len) {
            const float a = p[s] * inv;
            const float* r = bp + s * Hn;
            const float4 c0 = *reinterpret_cast<const float4*>(r + lane * 4);
            const float4 c1 = *reinterpret_cast<const float4*>(r + (lane + 64) * 4);
            const float4 c2 = *reinterpret_cast<const float4*>(r + (lane + 128) * 4);
            a0.x += a * c0.x; a0.y += a * c0.y; a0.z += a * c0.z; a0.w += a * c0.w;
            a1.x += a * c1.x; a1.y += a * c1.y; a1.z += a * c1.z; a1.w += a * c1.w;
            a2.x += a * c2.x; a2.y += a * c2.y; a2.z += a * c2.z; a2.w += a * c2.w;
        }
    }

    // ---- store ----
    if (isq) {
        for (int dd = 0; dd < Dn; ++dd) {
            float4* o = reinterpret_cast<float4*>(out_q + ((size_t)b * Dn + dd) * Hn);
            o[lane] = a0; o[lane + 64] = a1; o[lane + 128] = a2;
        }
    } else {
        float4* o = reinterpret_cast<float4*>(out_doc + ((size_t)b * Dn + d) * Hn);
        o[lane] = a0; o[lane + 64] = a1; o[lane + 128] = a2;
    }
}

extern "C" void kernel_launch(void* const* d_in, const int* in_sizes, int n_in,
                              void* d_out, int out_size, void* d_ws, size_t ws_size,
                              hipStream_t stream)
{
    const float* hs    = (const float*)d_in[0];   // (B,L,H) f32
    const float* Wd    = (const float*)d_in[1];   // (H,1)
    const float* Wq    = (const float*)d_in[3];   // (H,1)
    const int*   qlen  = (const int*)d_in[5];     // (B,)
    const int*   slens = (const int*)d_in[6];     // (B,D)
    // d_in[2] (b_doc) and d_in[4] (b_query) are unused: a uniform bias inside
    // a softmax cancels, and masked entries still underflow to exact 0.

    float* out_doc = (float*)d_out;                       // (B,D,H) doc_pooled
    float* out_q   = out_doc + (size_t)Bn * Dn * Hn;      // (B,D,H) q_bcast

    k_wave<<<Bn + Bn * Dn, 64, 0, stream>>>(hs, Wd, Wq, qlen, slens,
                                            out_doc, out_q);
}

// Round 11
// 17.313 us; speedup vs baseline: 2.2743x; 2.2743x over previous
//
#include <hip/hip_runtime.h>

namespace {
constexpr int Bn = 64;
constexpr int Ln = 512;
constexpr int Hn = 768;
constexpr int Dn = 16;
constexpr int Qn = 32;
constexpr float NEGV = -900000.0f;
}

// ---------------------------------------------------------------------------
// R5 structure with phase-2 re-read (occupancy probe).
// 256 threads = 4 waves; wave w owns rows {w, w+4, ...}.
//  Phase 1: per row, load 3 float4/lane (lane+64j covers 768 cols), dot with
//           W, 6-step shfl reduce, lane0 -> score_sh[s]. Registers DIE after
//           the dot (no keep) -> low VGPR -> 2x residency vs R5.
//  Softmax: masked width-32 in wave 0 (as R5).
//  Phase 2: re-load rows (L1/L2-hot, same CU just touched them), FMA into
//           float4 acc; fully unrolled, wave-uniform predicates -> ~21
//           independent loads in flight.
//  Combine: 4 wave partials via 12 KB LDS, per-thread scalar sums (as R5).
// ---------------------------------------------------------------------------
template<int NIT>
__device__ __forceinline__ void pool_span(
    const float* __restrict__ rowbase,   // &hs[(b*L + first_row) * H]
    const float* __restrict__ W, float bias, int len,
    float* __restrict__ score_sh, float (*pool_sh)[Hn],
    int t, int wave, int lane, float out3[3])
{
    float4 wv[3];
#pragma unroll
    for (int j = 0; j < 3; ++j)
        wv[j] = *reinterpret_cast<const float4*>(W + (lane + 64 * j) * 4);

    // phase 1: score rows (registers die after the dot)
#pragma unroll
    for (int it = 0; it < NIT; ++it) {
        const int s = wave + 4 * it;              // wave-uniform predicate
        if (s < len) {
            const float* r = rowbase + s * Hn;
            const float4 c0 = *reinterpret_cast<const float4*>(r + lane * 4);
            const float4 c1 = *reinterpret_cast<const float4*>(r + (lane + 64) * 4);
            const float4 c2 = *reinterpret_cast<const float4*>(r + (lane + 128) * 4);
            float p = c0.x * wv[0].x + c0.y * wv[0].y + c0.z * wv[0].z + c0.w * wv[0].w
                    + c1.x * wv[1].x + c1.y * wv[1].y + c1.z * wv[1].z + c1.w * wv[1].w
                    + c2.x * wv[2].x + c2.y * wv[2].y + c2.z * wv[2].z + c2.w * wv[2].w;
#pragma unroll
            for (int off = 32; off; off >>= 1) p += __shfl_down(p, off);
            if (lane == 0) score_sh[s] = p;
        }
    }
    __syncthreads();                              // barrier 1: scores ready

    // masked softmax in 32 lanes of wave 0; alpha (0 for masked) -> score_sh
    if (t < Qn) {
        const float raw = (t < len) ? (score_sh[t] + bias) : NEGV;
        float m = raw;
#pragma unroll
        for (int off = 16; off; off >>= 1) m = fmaxf(m, __shfl_xor(m, off, 32));
        const float e = expf(raw - m);
        float den = e;
#pragma unroll
        for (int off = 16; off; off >>= 1) den += __shfl_xor(den, off, 32);
        score_sh[t] = (t < len) ? (e / den) : 0.f;
    }
    __syncthreads();                              // barrier 2: alpha ready

    // phase 2: re-read rows (L1/L2-hot), weighted FMA
    float4 acc[3];
#pragma unroll
    for (int j = 0; j < 3; ++j) acc[j] = make_float4(0.f, 0.f, 0.f, 0.f);
#pragma unroll
    for (int it = 0; it < NIT; ++it) {
        const int s = wave + 4 * it;
        if (s < len) {
            const float a = score_sh[s];          // LDS broadcast
            const float* r = rowbase + s * Hn;
            const float4 c0 = *reinterpret_cast<const float4*>(r + lane * 4);
            const float4 c1 = *reinterpret_cast<const float4*>(r + (lane + 64) * 4);
            const float4 c2 = *reinterpret_cast<const float4*>(r + (lane + 128) * 4);
            acc[0].x += a * c0.x; acc[0].y += a * c0.y; acc[0].z += a * c0.z; acc[0].w += a * c0.w;
            acc[1].x += a * c1.x; acc[1].y += a * c1.y; acc[1].z += a * c1.z; acc[1].w += a * c1.w;
            acc[2].x += a * c2.x; acc[2].y += a * c2.y; acc[2].z += a * c2.z; acc[2].w += a * c2.w;
        }
    }

    // cross-wave combine through LDS (R5 form)
#pragma unroll
    for (int j = 0; j < 3; ++j)
        *reinterpret_cast<float4*>(&pool_sh[wave][(lane + 64 * j) * 4]) = acc[j];
    __syncthreads();                              // barrier 3: partials ready
    out3[0] = pool_sh[0][t]       + pool_sh[1][t]       + pool_sh[2][t]       + pool_sh[3][t];
    out3[1] = pool_sh[0][t + 256] + pool_sh[1][t + 256] + pool_sh[2][t + 256] + pool_sh[3][t + 256];
    out3[2] = pool_sh[0][t + 512] + pool_sh[1][t + 512] + pool_sh[2][t + 512] + pool_sh[3][t + 512];
}

__global__ __launch_bounds__(256) void k_fused(
    const float* __restrict__ hs,
    const float* __restrict__ Wd, const float* __restrict__ bd,
    const float* __restrict__ Wq, const float* __restrict__ bq,
    const int* __restrict__ qlen, const int* __restrict__ slens,
    float* __restrict__ out_doc, float* __restrict__ out_q)
{
    __shared__ float score_sh[Qn];
    __shared__ float pool_sh[4][Hn];      // 12 KB

    const int t = threadIdx.x;
    const int wave = t >> 6;
    const int lane = t & 63;
    const int bid = blockIdx.x;

    if (bid < Bn) {
        // ------------------------- query block -------------------------
        const int b = bid;
        const int ql = qlen[b];                            // 8..32
        const float* bp = hs + ((size_t)b * Ln + 1) * Hn;
        float o3[3];
        pool_span<8>(bp, Wq, bq[0], ql, score_sh, pool_sh, t, wave, lane, o3);
        for (int dd = 0; dd < Dn; ++dd) {
            float* o = out_q + ((size_t)b * Dn + dd) * Hn;
            o[t] = o3[0]; o[t + 256] = o3[1]; o[t + 512] = o3[2];
        }
    } else {
        // -------------------------- doc block --------------------------
        const int id = bid - Bn;
        const int b = id >> 4;
        const int d = id & 15;

        const int sv = slens[b * Dn + (lane & 15)];        // parallel prefix
        const int sl = __shfl(sv, d, 64);                  // this doc's len
        float* o = out_doc + ((size_t)b * Dn + d) * Hn;
        if (sl == 0) {                                     // ~36% of doc blocks
            o[t] = 0.f; o[t + 256] = 0.f; o[t + 512] = 0.f;
            return;
        }
        int pref = 0;
#pragma unroll
        for (int k = 0; k < Dn; ++k)
            pref += (k < d) ? __shfl(sv, k, 64) : 0;
        const int base = qlen[b] + 2 + pref;               // max valid idx 481 < 512
        const float* bp = hs + ((size_t)b * Ln + base) * Hn;
        float o3[3];
        pool_span<7>(bp, Wd, bd[0], sl, score_sh, pool_sh, t, wave, lane, o3);
        o[t] = o3[0]; o[t + 256] = o3[1]; o[t + 512] = o3[2];
    }
}

extern "C" void kernel_launch(void* const* d_in, const int* in_sizes, int n_in,
                              void* d_out, int out_size, void* d_ws, size_t ws_size,
                              hipStream_t stream)
{
    const float* hs    = (const float*)d_in[0];   // (B,L,H) f32
    const float* Wd    = (const float*)d_in[1];   // (H,1)
    const float* bd    = (const float*)d_in[2];   // (1,)
    const float* Wq    = (const float*)d_in[3];   // (H,1)
    const float* bq    = (const float*)d_in[4];   // (1,)
    const int*   qlen  = (const int*)d_in[5];     // (B,)
    const int*   slens = (const int*)d_in[6];     // (B,D)

    float* out_doc = (float*)d_out;                       // (B,D,H) doc_pooled
    float* out_q   = out_doc + (size_t)Bn * Dn * Hn;      // (B,D,H) q_bcast

    k_fused<<<Bn + Bn * Dn, 256, 0, stream>>>(hs, Wd, bd, Wq, bq,
                                              qlen, slens, out_doc, out_q);
}

// Round 12
// 15.372 us; speedup vs baseline: 2.5615x; 1.1263x over previous
//
#include <hip/hip_runtime.h>

namespace {
constexpr int Bn = 64;
constexpr int Ln = 512;
constexpr int Hn = 768;
constexpr int Dn = 16;
constexpr int Qn = 32;
constexpr float NEGV = -900000.0f;
}

// ---------------------------------------------------------------------------
// R5 structure (best: 16.4 us) with ONE change: phase 1 is split into
//   (1a) a pure LOAD loop filling c[NIT][3]   — no consumption, so all ~21
//        loads per wave go in flight together (no per-iteration waitcnt)
//   (1b) a separate DOT loop consuming c[] in issue order (partial vmcnt
//        drains)
// Everything else identical to R5: 256 threads = 4 waves; wave w owns rows
// {w, w+4, ...}; wave-0 masked width-32 softmax; phase 2 pure register FMA
// on the kept rows; 12 KB LDS cross-wave combine; scalar epilogue.
// Every hidden_states byte read exactly once, as dwordx4.
// ---------------------------------------------------------------------------
template<int NIT>
__device__ __forceinline__ void pool_span(
    const float* __restrict__ rowbase,   // &hs[(b*L + first_row) * H]
    const float* __restrict__ W, float bias, int len,
    float* __restrict__ score_sh, float (*pool_sh)[Hn],
    int t, int wave, int lane, float out3[3])
{
    float4 wv[3];
#pragma unroll
    for (int j = 0; j < 3; ++j)
        wv[j] = *reinterpret_cast<const float4*>(W + (lane + 64 * j) * 4);

    // ---- phase 1a: pure load loop — all rows' loads in flight together ----
    float4 c[NIT][3];
#pragma unroll
    for (int it = 0; it < NIT; ++it) {
        const int s = wave + 4 * it;              // wave-uniform predicate
        if (s < len) {
            const float* r = rowbase + s * Hn;
#pragma unroll
            for (int j = 0; j < 3; ++j)
                c[it][j] = *reinterpret_cast<const float4*>(r + (lane + 64 * j) * 4);
        }
    }

    // ---- phase 1b: dot + reduce, consuming in issue order ----
#pragma unroll
    for (int it = 0; it < NIT; ++it) {
        const int s = wave + 4 * it;
        if (s < len) {
            float p = c[it][0].x * wv[0].x + c[it][0].y * wv[0].y
                    + c[it][0].z * wv[0].z + c[it][0].w * wv[0].w
                    + c[it][1].x * wv[1].x + c[it][1].y * wv[1].y
                    + c[it][1].z * wv[1].z + c[it][1].w * wv[1].w
                    + c[it][2].x * wv[2].x + c[it][2].y * wv[2].y
                    + c[it][2].z * wv[2].z + c[it][2].w * wv[2].w;
#pragma unroll
            for (int off = 32; off; off >>= 1) p += __shfl_down(p, off);
            if (lane == 0) score_sh[s] = p;
        }
    }
    __syncthreads();                              // barrier 1: scores ready

    // masked softmax in 32 lanes of wave 0; alpha (0 for masked) -> score_sh
    if (t < Qn) {
        const float raw = (t < len) ? (score_sh[t] + bias) : NEGV;
        float m = raw;
#pragma unroll
        for (int off = 16; off; off >>= 1) m = fmaxf(m, __shfl_xor(m, off, 32));
        const float e = expf(raw - m);
        float den = e;
#pragma unroll
        for (int off = 16; off; off >>= 1) den += __shfl_xor(den, off, 32);
        score_sh[t] = (t < len) ? (e / den) : 0.f;
    }
    __syncthreads();                              // barrier 2: alpha ready

    // phase 2: pure register FMA per wave (alpha via LDS broadcast)
    float4 acc[3];
#pragma unroll
    for (int j = 0; j < 3; ++j) acc[j] = make_float4(0.f, 0.f, 0.f, 0.f);
#pragma unroll
    for (int it = 0; it < NIT; ++it) {
        const int s = wave + 4 * it;
        if (s < len) {
            const float a = score_sh[s];
#pragma unroll
            for (int j = 0; j < 3; ++j) {
                acc[j].x += a * c[it][j].x;
                acc[j].y += a * c[it][j].y;
                acc[j].z += a * c[it][j].z;
                acc[j].w += a * c[it][j].w;
            }
        }
    }

    // cross-wave combine through LDS
#pragma unroll
    for (int j = 0; j < 3; ++j)
        *reinterpret_cast<float4*>(&pool_sh[wave][(lane + 64 * j) * 4]) = acc[j];
    __syncthreads();                              // barrier 3: partials ready
    out3[0] = pool_sh[0][t]       + pool_sh[1][t]       + pool_sh[2][t]       + pool_sh[3][t];
    out3[1] = pool_sh[0][t + 256] + pool_sh[1][t + 256] + pool_sh[2][t + 256] + pool_sh[3][t + 256];
    out3[2] = pool_sh[0][t + 512] + pool_sh[1][t + 512] + pool_sh[2][t + 512] + pool_sh[3][t + 512];
}

__global__ __launch_bounds__(256) void k_fused(
    const float* __restrict__ hs,
    const float* __restrict__ Wd, const float* __restrict__ bd,
    const float* __restrict__ Wq, const float* __restrict__ bq,
    const int* __restrict__ qlen, const int* __restrict__ slens,
    float* __restrict__ out_doc, float* __restrict__ out_q)
{
    __shared__ float score_sh[Qn];
    __shared__ float pool_sh[4][Hn];      // 12 KB

    const int t = threadIdx.x;
    const int wave = t >> 6;
    const int lane = t & 63;
    const int bid = blockIdx.x;

    if (bid < Bn) {
        // ------------------------- query block -------------------------
        const int b = bid;
        const int ql = qlen[b];                            // 8..32
        const float* bp = hs + ((size_t)b * Ln + 1) * Hn;
        float o3[3];
        pool_span<8>(bp, Wq, bq[0], ql, score_sh, pool_sh, t, wave, lane, o3);
        for (int dd = 0; dd < Dn; ++dd) {
            float* o = out_q + ((size_t)b * Dn + dd) * Hn;
            o[t] = o3[0]; o[t + 256] = o3[1]; o[t + 512] = o3[2];
        }
    } else {
        // -------------------------- doc block --------------------------
        const int id = bid - Bn;
        const int b = id >> 4;
        const int d = id & 15;

        const int sv = slens[b * Dn + (lane & 15)];        // parallel prefix
        const int sl = __shfl(sv, d, 64);                  // this doc's len
        float* o = out_doc + ((size_t)b * Dn + d) * Hn;
        if (sl == 0) {                                     // ~36% of doc blocks
            o[t] = 0.f; o[t + 256] = 0.f; o[t + 512] = 0.f;
            return;
        }
        int pref = 0;
#pragma unroll
        for (int k = 0; k < Dn; ++k)
            pref += (k < d) ? __shfl(sv, k, 64) : 0;
        const int base = qlen[b] + 2 + pref;               // max valid idx 481 < 512
        const float* bp = hs + ((size_t)b * Ln + base) * Hn;
        float o3[3];
        pool_span<7>(bp, Wd, bd[0], sl, score_sh, pool_sh, t, wave, lane, o3);
        o[t] = o3[0]; o[t + 256] = o3[1]; o[t + 512] = o3[2];
    }
}

extern "C" void kernel_launch(void* const* d_in, const int* in_sizes, int n_in,
                              void* d_out, int out_size, void* d_ws, size_t ws_size,
                              hipStream_t stream)
{
    const float* hs    = (const float*)d_in[0];   // (B,L,H) f32
    const float* Wd    = (const float*)d_in[1];   // (H,1)
    const float* bd    = (const float*)d_in[2];   // (1,)
    const float* Wq    = (const float*)d_in[3];   // (H,1)
    const float* bq    = (const float*)d_in[4];   // (1,)
    const int*   qlen  = (const int*)d_in[5];     // (B,)
    const int*   slens = (const int*)d_in[6];     // (B,D)

    float* out_doc = (float*)d_out;                       // (B,D,H) doc_pooled
    float* out_q   = out_doc + (size_t)Bn * Dn * Hn;      // (B,D,H) q_bcast

    k_fused<<<Bn + Bn * Dn, 256, 0, stream>>>(hs, Wd, bd, Wq, bq,
                                              qlen, slens, out_doc, out_q);
}

// Round 13
// 15.236 us; speedup vs baseline: 2.5843x; 1.0089x over previous
//
#include <hip/hip_runtime.h>

namespace {
constexpr int Bn = 64;
constexpr int Ln = 512;
constexpr int Hn = 768;
constexpr int Dn = 16;
constexpr int Qn = 32;
constexpr float NEGV = -900000.0f;
}

// ---------------------------------------------------------------------------
// R12 (best: 15.37 us) + bias-drop (softmax shift-invariance; validated in
// R10) + __expf. Structure:
//  Phase 1a: pure load loop filling c[NIT][3] — all ~21 loads/wave in flight
//  Phase 1b: dot + 6-step shfl reduce, consuming in issue order
//  wave-0 masked width-32 softmax (no bias: uniform shift cancels; masked
//  entries still underflow to exact 0)
//  Phase 2: pure register FMA on kept rows; 12 KB LDS cross-wave combine.
// Every hidden_states byte read exactly once, as dwordx4.
// ---------------------------------------------------------------------------
template<int NIT>
__device__ __forceinline__ void pool_span(
    const float* __restrict__ rowbase,   // &hs[(b*L + first_row) * H]
    const float* __restrict__ W, int len,
    float* __restrict__ score_sh, float (*pool_sh)[Hn],
    int t, int wave, int lane, float out3[3])
{
    float4 wv[3];
#pragma unroll
    for (int j = 0; j < 3; ++j)
        wv[j] = *reinterpret_cast<const float4*>(W + (lane + 64 * j) * 4);

    // ---- phase 1a: pure load loop — all rows' loads in flight together ----
    float4 c[NIT][3];
#pragma unroll
    for (int it = 0; it < NIT; ++it) {
        const int s = wave + 4 * it;              // wave-uniform predicate
        if (s < len) {
            const float* r = rowbase + s * Hn;
#pragma unroll
            for (int j = 0; j < 3; ++j)
                c[it][j] = *reinterpret_cast<const float4*>(r + (lane + 64 * j) * 4);
        }
    }

    // ---- phase 1b: dot + reduce, consuming in issue order ----
#pragma unroll
    for (int it = 0; it < NIT; ++it) {
        const int s = wave + 4 * it;
        if (s < len) {
            float p = c[it][0].x * wv[0].x + c[it][0].y * wv[0].y
                    + c[it][0].z * wv[0].z + c[it][0].w * wv[0].w
                    + c[it][1].x * wv[1].x + c[it][1].y * wv[1].y
                    + c[it][1].z * wv[1].z + c[it][1].w * wv[1].w
                    + c[it][2].x * wv[2].x + c[it][2].y * wv[2].y
                    + c[it][2].z * wv[2].z + c[it][2].w * wv[2].w;
#pragma unroll
            for (int off = 32; off; off >>= 1) p += __shfl_down(p, off);
            if (lane == 0) score_sh[s] = p;
        }
    }
    __syncthreads();                              // barrier 1: scores ready

    // masked softmax in 32 lanes of wave 0 (biasless); alpha -> score_sh
    if (t < Qn) {
        const float raw = (t < len) ? score_sh[t] : NEGV;
        float m = raw;
#pragma unroll
        for (int off = 16; off; off >>= 1) m = fmaxf(m, __shfl_xor(m, off, 32));
        const float e = __expf(raw - m);
        float den = e;
#pragma unroll
        for (int off = 16; off; off >>= 1) den += __shfl_xor(den, off, 32);
        score_sh[t] = (t < len) ? (e / den) : 0.f;
    }
    __syncthreads();                              // barrier 2: alpha ready

    // phase 2: pure register FMA per wave (alpha via LDS broadcast)
    float4 acc[3];
#pragma unroll
    for (int j = 0; j < 3; ++j) acc[j] = make_float4(0.f, 0.f, 0.f, 0.f);
#pragma unroll
    for (int it = 0; it < NIT; ++it) {
        const int s = wave + 4 * it;
        if (s < len) {
            const float a = score_sh[s];
#pragma unroll
            for (int j = 0; j < 3; ++j) {
                acc[j].x += a * c[it][j].x;
                acc[j].y += a * c[it][j].y;
                acc[j].z += a * c[it][j].z;
                acc[j].w += a * c[it][j].w;
            }
        }
    }

    // cross-wave combine through LDS
#pragma unroll
    for (int j = 0; j < 3; ++j)
        *reinterpret_cast<float4*>(&pool_sh[wave][(lane + 64 * j) * 4]) = acc[j];
    __syncthreads();                              // barrier 3: partials ready
    out3[0] = pool_sh[0][t]       + pool_sh[1][t]       + pool_sh[2][t]       + pool_sh[3][t];
    out3[1] = pool_sh[0][t + 256] + pool_sh[1][t + 256] + pool_sh[2][t + 256] + pool_sh[3][t + 256];
    out3[2] = pool_sh[0][t + 512] + pool_sh[1][t + 512] + pool_sh[2][t + 512] + pool_sh[3][t + 512];
}

__global__ __launch_bounds__(256) void k_fused(
    const float* __restrict__ hs,
    const float* __restrict__ Wd,
    const float* __restrict__ Wq,
    const int* __restrict__ qlen, const int* __restrict__ slens,
    float* __restrict__ out_doc, float* __restrict__ out_q)
{
    __shared__ float score_sh[Qn];
    __shared__ float pool_sh[4][Hn];      // 12 KB

    const int t = threadIdx.x;
    const int wave = t >> 6;
    const int lane = t & 63;
    const int bid = blockIdx.x;

    if (bid < Bn) {
        // ------------------------- query block -------------------------
        const int b = bid;
        const int ql = qlen[b];                            // 8..32
        const float* bp = hs + ((size_t)b * Ln + 1) * Hn;
        float o3[3];
        pool_span<8>(bp, Wq, ql, score_sh, pool_sh, t, wave, lane, o3);
        for (int dd = 0; dd < Dn; ++dd) {
            float* o = out_q + ((size_t)b * Dn + dd) * Hn;
            o[t] = o3[0]; o[t + 256] = o3[1]; o[t + 512] = o3[2];
        }
    } else {
        // -------------------------- doc block --------------------------
        const int id = bid - Bn;
        const int b = id >> 4;
        const int d = id & 15;

        const int sv = slens[b * Dn + (lane & 15)];        // parallel prefix
        const int sl = __shfl(sv, d, 64);                  // this doc's len
        float* o = out_doc + ((size_t)b * Dn + d) * Hn;
        if (sl == 0) {                                     // ~36% of doc blocks
            o[t] = 0.f; o[t + 256] = 0.f; o[t + 512] = 0.f;
            return;
        }
        int pref = 0;
#pragma unroll
        for (int k = 0; k < Dn; ++k)
            pref += (k < d) ? __shfl(sv, k, 64) : 0;
        const int base = qlen[b] + 2 + pref;               // max valid idx 481 < 512
        const float* bp = hs + ((size_t)b * Ln + base) * Hn;
        float o3[3];
        pool_span<7>(bp, Wd, sl, score_sh, pool_sh, t, wave, lane, o3);
        o[t] = o3[0]; o[t + 256] = o3[1]; o[t + 512] = o3[2];
    }
}

extern "C" void kernel_launch(void* const* d_in, const int* in_sizes, int n_in,
                              void* d_out, int out_size, void* d_ws, size_t ws_size,
                              hipStream_t stream)
{
    const float* hs    = (const float*)d_in[0];   // (B,L,H) f32
    const float* Wd    = (const float*)d_in[1];   // (H,1)
    const float* Wq    = (const float*)d_in[3];   // (H,1)
    const int*   qlen  = (const int*)d_in[5];     // (B,)
    const int*   slens = (const int*)d_in[6];     // (B,D)
    // d_in[2] (b_doc) / d_in[4] (b_query) unused: uniform bias inside a
    // softmax cancels; masked entries still underflow to exact 0 (R10-validated).

    float* out_doc = (float*)d_out;                       // (B,D,H) doc_pooled
    float* out_q   = out_doc + (size_t)Bn * Dn * Hn;      // (B,D,H) q_bcast

    k_fused<<<Bn + Bn * Dn, 256, 0, stream>>>(hs, Wd, Wq, qlen, slens,
                                              out_doc, out_q);
}